// Round 3
// baseline (754.932 us; speedup 1.0000x reference)
//
#include <hip/hip_runtime.h>
#include <hip/hip_bf16.h>

#define NUM_EXPERTS 32
#define HIDDEN 2048
#define INTER 768
#define TOPK 4
#define T_TOKENS 1024
#define CAP 1024

#define MT 64       // token slots per block (z-split x3, stride-192 safety loop)
#define BK 64       // K step
#define LSTR 72     // LDS row stride in bf16 elements (16B-multiple, 144B rotates banks)
#define NT1 (HIDDEN / BK)   // 32 K-steps in gemm1
#define NT2 (INTER / BK)    // 12 K-steps in gemm2

typedef __bf16 bf16x8 __attribute__((ext_vector_type(8)));
typedef float floatx4 __attribute__((ext_vector_type(4)));

// XOR-swizzled LDS element offset: row-major stride LSTR, 8-elem (16B) k-blocks
// swizzled by row>>2 to break the n=4*lane staging-write bank pattern.
__device__ __forceinline__ int swz(int row, int kq) {
    return row * LSTR + (((kq ^ (row >> 2)) & 7) << 3);
}

// ---------------------------------------------------------------- routing ---
__global__ void route_kernel(const int* __restrict__ ri, int* __restrict__ counts,
                             int* __restrict__ tok_list) {
    int t = blockIdx.x * blockDim.x + threadIdx.x;
    if (t >= T_TOKENS) return;
    int idx[TOPK];
#pragma unroll
    for (int j = 0; j < TOPK; ++j) idx[j] = ri[t * TOPK + j];
#pragma unroll
    for (int j = 0; j < TOPK; ++j) {
        int e = idx[j];
        bool dup = false;
#pragma unroll
        for (int l = 0; l < TOPK; ++l)
            if (l < j && idx[l] == e) dup = true;
        if (!dup) {
            int s = atomicAdd(&counts[e], 1);
            tok_list[e * CAP + s] = t;
        }
    }
}

// ------------------------------------------------------- gemm1: x @ Wgu -----
// grid (3*INTER/64, E), z folded fastest for L3 sharing of the weight slab.
// Pipeline: double-buffered LDS, ONE barrier per K-step, 2-deep ping-pong
// register prefetch (named regsets -> compiler emits counted vmcnt; ds_write
// of tile j waits only on loads issued 2 K-steps earlier).
__global__ __launch_bounds__(256, 2) void gemm1_kernel(
    const float* __restrict__ x, const float* __restrict__ rw,
    const float* __restrict__ Wgu, const int* __restrict__ counts,
    const int* __restrict__ tok_list, __bf16* __restrict__ act) {
    const int e = blockIdx.y;
    const int zi = blockIdx.x % 3;
    const int n0 = (blockIdx.x / 3) * 64;
    const int count = counts[e];
    const int tid = threadIdx.x;
    const int wave = tid >> 6;
    const int lane = tid & 63;
    const int fr = lane & 15;
    const int fq = lane >> 4;
    const int wr = wave >> 1;   // wave M-half
    const int wc = wave & 1;    // wave N-half

    __shared__ int s_off;
    __shared__ int s_tok[MT];
    __shared__ float s_w[MT];
    __shared__ __align__(16) __bf16 As[2][MT * LSTR];
    __shared__ __align__(16) __bf16 Bs[2][128 * LSTR];

    if (tid == 0) {
        int o = 0;
        for (int i = 0; i < e; ++i) o += counts[i];
        s_off = o;
    }

    const size_t wbase = (size_t)e * HIDDEN * (2 * INTER);

    // B staging geometry: thread owns 4 adjacent n, 8 k rows
    const int ng = (tid & 31) * 4;
    const int kg = tid >> 5;
    const int bwc = ng >> 6;
    const int bj = ng & 63;
    const int memcol = (bj < 32) ? (n0 + bwc * 32 + bj)
                                 : (INTER + n0 + bwc * 32 + (bj - 32));
    // A staging geometry
    const int ar = tid >> 2;
    const int aq = tid & 3;

    for (int m0 = zi * MT; m0 < count; m0 += 3 * MT) {
        __syncthreads();
        if (tid < MT) {
            int slot = m0 + tid;
            int t = (slot < count) ? tok_list[e * CAP + slot] : tok_list[e * CAP];
            s_tok[tid] = t;
            s_w[tid] = (slot < count) ? rw[t * NUM_EXPERTS + e] : 0.f;
        }
        __syncthreads();

        const float* aRow = x + (size_t)s_tok[ar] * HIDDEN + aq * 16;
        const float* bCol = Wgu + wbase + (size_t)(kg * 8) * (2 * INTER) + memcol;

        float4 a0[4], a1[4], b0[8], b1[8];

        auto loadA = [&](float4* pa, int kb) {
            const float4* s = (const float4*)(aRow + kb);
#pragma unroll
            for (int i = 0; i < 4; ++i) pa[i] = s[i];
        };
        auto loadB = [&](float4* pb, int kb) {
#pragma unroll
            for (int r8 = 0; r8 < 8; ++r8)
                pb[r8] = *(const float4*)(bCol + (size_t)(kb + r8) * (2 * INTER));
        };
        auto writeA = [&](__bf16* Ad, const float4* pa) {
            bf16x8 p0, p1;
            p0[0] = (__bf16)pa[0].x; p0[1] = (__bf16)pa[0].y; p0[2] = (__bf16)pa[0].z; p0[3] = (__bf16)pa[0].w;
            p0[4] = (__bf16)pa[1].x; p0[5] = (__bf16)pa[1].y; p0[6] = (__bf16)pa[1].z; p0[7] = (__bf16)pa[1].w;
            p1[0] = (__bf16)pa[2].x; p1[1] = (__bf16)pa[2].y; p1[2] = (__bf16)pa[2].z; p1[3] = (__bf16)pa[2].w;
            p1[4] = (__bf16)pa[3].x; p1[5] = (__bf16)pa[3].y; p1[6] = (__bf16)pa[3].z; p1[7] = (__bf16)pa[3].w;
            *(bf16x8*)&Ad[swz(ar, 2 * aq)] = p0;
            *(bf16x8*)&Ad[swz(ar, 2 * aq + 1)] = p1;
        };
        auto writeB = [&](__bf16* Bd, const float4* pb) {
#pragma unroll
            for (int c = 0; c < 4; ++c) {
                bf16x8 p;
#pragma unroll
                for (int r8 = 0; r8 < 8; ++r8)
                    p[r8] = (__bf16)((const float*)&pb[r8])[c];
                *(bf16x8*)&Bd[swz(ng + c, kg)] = p;
            }
        };

        floatx4 acc[2][4];
#pragma unroll
        for (int ms = 0; ms < 2; ++ms)
#pragma unroll
            for (int nf = 0; nf < 4; ++nf)
                acc[ms][nf] = (floatx4){0.f, 0.f, 0.f, 0.f};

        auto compute = [&](const __bf16* Ad, const __bf16* Bd) {
#pragma unroll
            for (int ks = 0; ks < 2; ++ks) {
                bf16x8 af[2], bfr[4];
#pragma unroll
                for (int ms = 0; ms < 2; ++ms)
                    af[ms] = *(const bf16x8*)&Ad[swz(wr * 32 + ms * 16 + fr, ks * 4 + fq)];
#pragma unroll
                for (int nf = 0; nf < 4; ++nf)
                    bfr[nf] = *(const bf16x8*)&Bd[swz(wc * 64 + nf * 16 + fr, ks * 4 + fq)];
#pragma unroll
                for (int ms = 0; ms < 2; ++ms)
#pragma unroll
                    for (int nf = 0; nf < 4; ++nf)
                        acc[ms][nf] = __builtin_amdgcn_mfma_f32_16x16x32_bf16(af[ms], bfr[nf], acc[ms][nf], 0, 0, 0);
            }
        };

        // pipeline prologue: tiles 0,1 loaded; tile0 -> buf0; tile2 issued
        loadA(a0, 0);          loadB(b0, 0);
        loadA(a1, BK);         loadB(b1, BK);
        writeA(As[0], a0);     writeB(Bs[0], b0);
        loadA(a0, 2 * BK);     loadB(b0, 2 * BK);
        __syncthreads();

        for (int it = 0; it < NT1; it += 2) {
            // even tile 'it' in buf0; write tile it+1 -> buf1; issue tile it+3
            if (it + 1 < NT1) {
                writeA(As[1], a1); writeB(Bs[1], b1);
                if (it + 3 < NT1) { loadA(a1, (it + 3) * BK); loadB(b1, (it + 3) * BK); }
            }
            compute(As[0], Bs[0]);
            if (it + 1 >= NT1) break;
            __syncthreads();
            // odd tile 'it+1' in buf1; write tile it+2 -> buf0; issue tile it+4
            if (it + 2 < NT1) {
                writeA(As[0], a0); writeB(Bs[0], b0);
                if (it + 4 < NT1) { loadA(a0, (it + 4) * BK); loadB(b0, (it + 4) * BK); }
            }
            compute(As[1], Bs[1]);
            if (it + 2 < NT1) __syncthreads();
        }

        // epilogue: silu(gate)*up*rw -> act bf16 (frags nf<2 gate, nf>=2 up)
        const int off = s_off;
#pragma unroll
        for (int ms = 0; ms < 2; ++ms) {
            int rbase = wr * 32 + ms * 16 + fq * 4;
#pragma unroll
            for (int i = 0; i < 4; ++i) {
                int slot = m0 + rbase + i;
                if (slot < count) {
                    float w = s_w[rbase + i];
#pragma unroll
                    for (int nf = 0; nf < 2; ++nf) {
                        float gv = acc[ms][nf][i];
                        float uv = acc[ms][nf + 2][i];
                        float a = gv / (1.f + __expf(-gv)) * uv * w;
                        act[(size_t)(off + slot) * INTER + n0 + wc * 32 + nf * 16 + fr] = (__bf16)a;
                    }
                }
            }
        }
    }
}

// ------------------------------------------------- gemm2: act @ Wd -> out ---
// grid (3*HIDDEN/128, E). Same single-barrier double-buffer pipeline.
__global__ __launch_bounds__(256, 2) void gemm2_kernel(
    const __bf16* __restrict__ act, const float* __restrict__ Wd,
    const int* __restrict__ counts, const int* __restrict__ tok_list,
    float* __restrict__ out) {
    const int e = blockIdx.y;
    const int zi = blockIdx.x % 3;
    const int n0 = (blockIdx.x / 3) * 128;
    const int count = counts[e];
    const int tid = threadIdx.x;
    const int wave = tid >> 6;
    const int lane = tid & 63;
    const int fr = lane & 15;
    const int fq = lane >> 4;
    const int wr = wave >> 1;
    const int wc = wave & 1;

    __shared__ int s_off;
    __shared__ int s_tok[MT];
    __shared__ __align__(16) __bf16 As[2][MT * LSTR];
    __shared__ __align__(16) __bf16 Bs[2][128 * LSTR];

    if (tid == 0) {
        int o = 0;
        for (int i = 0; i < e; ++i) o += counts[i];
        s_off = o;
    }

    const size_t wbase = (size_t)e * INTER * HIDDEN;
    const int ng = (tid & 31) * 4;
    const int kg = tid >> 5;
    const int ar = tid >> 2;
    const int aq = tid & 3;

    for (int m0 = zi * MT; m0 < count; m0 += 3 * MT) {
        __syncthreads();
        if (tid < MT) {
            int slot = m0 + tid;
            s_tok[tid] = (slot < count) ? tok_list[e * CAP + slot] : 0;
        }
        __syncthreads();

        const __bf16* aRow = act + (size_t)(s_off + min(m0 + ar, count - 1)) * INTER + aq * 16;
        const float* bCol = Wd + wbase + (size_t)(kg * 8) * HIDDEN + n0 + ng;

        bf16x8 qa0[2], qa1[2];
        float4 b0[8], b1[8];

        auto loadA = [&](bf16x8* qa, int kb) {
            const bf16x8* s = (const bf16x8*)(aRow + kb);
            qa[0] = s[0];
            qa[1] = s[1];
        };
        auto loadB = [&](float4* pb, int kb) {
#pragma unroll
            for (int r8 = 0; r8 < 8; ++r8)
                pb[r8] = *(const float4*)(bCol + (size_t)(kb + r8) * HIDDEN);
        };
        auto writeA = [&](__bf16* Ad, const bf16x8* qa) {
            *(bf16x8*)&Ad[swz(ar, 2 * aq)] = qa[0];
            *(bf16x8*)&Ad[swz(ar, 2 * aq + 1)] = qa[1];
        };
        auto writeB = [&](__bf16* Bd, const float4* pb) {
#pragma unroll
            for (int c = 0; c < 4; ++c) {
                bf16x8 p;
#pragma unroll
                for (int r8 = 0; r8 < 8; ++r8)
                    p[r8] = (__bf16)((const float*)&pb[r8])[c];
                *(bf16x8*)&Bd[swz(ng + c, kg)] = p;
            }
        };

        floatx4 acc[2][4];
#pragma unroll
        for (int ms = 0; ms < 2; ++ms)
#pragma unroll
            for (int nf = 0; nf < 4; ++nf)
                acc[ms][nf] = (floatx4){0.f, 0.f, 0.f, 0.f};

        auto compute = [&](const __bf16* Ad, const __bf16* Bd) {
#pragma unroll
            for (int ks = 0; ks < 2; ++ks) {
                bf16x8 af[2], bfr[4];
#pragma unroll
                for (int ms = 0; ms < 2; ++ms)
                    af[ms] = *(const bf16x8*)&Ad[swz(wr * 32 + ms * 16 + fr, ks * 4 + fq)];
#pragma unroll
                for (int nf = 0; nf < 4; ++nf)
                    bfr[nf] = *(const bf16x8*)&Bd[swz(wc * 64 + nf * 16 + fr, ks * 4 + fq)];
#pragma unroll
                for (int ms = 0; ms < 2; ++ms)
#pragma unroll
                    for (int nf = 0; nf < 4; ++nf)
                        acc[ms][nf] = __builtin_amdgcn_mfma_f32_16x16x32_bf16(af[ms], bfr[nf], acc[ms][nf], 0, 0, 0);
            }
        };

        // pipeline prologue
        loadA(qa0, 0);          loadB(b0, 0);
        loadA(qa1, BK);         loadB(b1, BK);
        writeA(As[0], qa0);     writeB(Bs[0], b0);
        loadA(qa0, 2 * BK);     loadB(b0, 2 * BK);
        __syncthreads();

        for (int it = 0; it < NT2; it += 2) {
            if (it + 1 < NT2) {
                writeA(As[1], qa1); writeB(Bs[1], b1);
                if (it + 3 < NT2) { loadA(qa1, (it + 3) * BK); loadB(b1, (it + 3) * BK); }
            }
            compute(As[0], Bs[0]);
            if (it + 1 >= NT2) break;
            __syncthreads();
            if (it + 2 < NT2) {
                writeA(As[0], qa0); writeB(Bs[0], b0);
                if (it + 4 < NT2) { loadA(qa0, (it + 4) * BK); loadB(b0, (it + 4) * BK); }
            }
            compute(As[1], Bs[1]);
            if (it + 2 < NT2) __syncthreads();
        }

        // epilogue: scatter-accumulate f32 atomics
#pragma unroll
        for (int ms = 0; ms < 2; ++ms) {
            int rbase = wr * 32 + ms * 16 + fq * 4;
#pragma unroll
            for (int i = 0; i < 4; ++i) {
                int slot = m0 + rbase + i;
                if (slot < count) {
                    int t = s_tok[rbase + i];
#pragma unroll
                    for (int nf = 0; nf < 4; ++nf)
                        atomicAdd(&out[(size_t)t * HIDDEN + n0 + wc * 64 + nf * 16 + fr], acc[ms][nf][i]);
                }
            }
        }
    }
}

// ---------------------------------------------------------------- launch ----
extern "C" void kernel_launch(void* const* d_in, const int* in_sizes, int n_in,
                              void* d_out, int out_size, void* d_ws, size_t ws_size,
                              hipStream_t stream) {
    const float* x   = (const float*)d_in[0];
    const float* rw  = (const float*)d_in[1];
    const float* Wgu = (const float*)d_in[2];
    const float* Wd  = (const float*)d_in[3];
    const int*   ri  = (const int*)d_in[4];
    float* out = (float*)d_out;

    int* counts   = (int*)d_ws;
    int* tok_list = (int*)((char*)d_ws + 512);
    __bf16* act   = (__bf16*)((char*)d_ws + 512 + NUM_EXPERTS * CAP * 4);

    hipMemsetAsync(d_ws, 0, 512, stream);
    hipMemsetAsync(d_out, 0, (size_t)T_TOKENS * HIDDEN * sizeof(float), stream);

    route_kernel<<<dim3(T_TOKENS / 256), 256, 0, stream>>>(ri, counts, tok_list);
    gemm1_kernel<<<dim3(3 * INTER / 64, NUM_EXPERTS), 256, 0, stream>>>(x, rw, Wgu, counts, tok_list, act);
    gemm2_kernel<<<dim3(3 * HIDDEN / 128, NUM_EXPERTS), 256, 0, stream>>>(act, Wd, counts, tok_list, out);
}

// Round 4
// 705.523 us; speedup vs baseline: 1.0700x; 1.0700x over previous
//
#include <hip/hip_runtime.h>
#include <hip/hip_bf16.h>

#define NUM_EXPERTS 32
#define HIDDEN 2048
#define INTER 768
#define TOPK 4
#define T_TOKENS 1024
#define CAP 1024

#define MW 192      // token window per block (3 x 64-row MFMA tiles)
#define BK 64       // K step
#define LSTR 72     // LDS row stride in bf16 elements (16B-multiple)

typedef __bf16 bf16x8 __attribute__((ext_vector_type(8)));
typedef float floatx4 __attribute__((ext_vector_type(4)));

// XOR-swizzled LDS element offset: row-major stride LSTR, 8-elem (16B) k-blocks
// swizzled by row>>2 to break the staging-write bank pattern.
__device__ __forceinline__ int swz(int row, int kq) {
    return row * LSTR + (((kq ^ (row >> 2)) & 7) << 3);
}

// ---------------------------------------------------------------- routing ---
__global__ void route_kernel(const int* __restrict__ ri, int* __restrict__ counts,
                             int* __restrict__ tok_list) {
    int t = blockIdx.x * blockDim.x + threadIdx.x;
    if (t >= T_TOKENS) return;
    int idx[TOPK];
#pragma unroll
    for (int j = 0; j < TOPK; ++j) idx[j] = ri[t * TOPK + j];
#pragma unroll
    for (int j = 0; j < TOPK; ++j) {
        int e = idx[j];
        bool dup = false;
#pragma unroll
        for (int l = 0; l < TOPK; ++l)
            if (l < j && idx[l] == e) dup = true;
        if (!dup) {
            int s = atomicAdd(&counts[e], 1);
            tok_list[e * CAP + s] = t;
        }
    }
}

// ------------------------------------------------ x -> bf16 pre-convert ----
__global__ __launch_bounds__(256) void conv_kernel(const float* __restrict__ x,
                                                   __bf16* __restrict__ xb) {
    int i = (blockIdx.x * 256 + threadIdx.x) * 8;
    float4 f0 = *(const float4*)(x + i);
    float4 f1 = *(const float4*)(x + i + 4);
    bf16x8 p;
    p[0] = (__bf16)f0.x; p[1] = (__bf16)f0.y; p[2] = (__bf16)f0.z; p[3] = (__bf16)f0.w;
    p[4] = (__bf16)f1.x; p[5] = (__bf16)f1.y; p[6] = (__bf16)f1.z; p[7] = (__bf16)f1.w;
    *(bf16x8*)(xb + i) = p;
}

// ------------------------------------------------------- gemm1: x @ Wgu -----
// grid (INTER/64, E): ONE block per weight slab -> every weight byte is
// requested exactly once. The block loops all of its expert's tokens as up to
// 3 x 64-row tiles INSIDE each K-step, reusing the staged weight tile.
// T14 split: next K-tile loads issued before compute, written after barrier.
__global__ __launch_bounds__(256, 2) void gemm1_kernel(
    const __bf16* __restrict__ xb, const float* __restrict__ rw,
    const float* __restrict__ Wgu, const int* __restrict__ counts,
    const int* __restrict__ tok_list, __bf16* __restrict__ act) {
    const int e = blockIdx.y;
    const int n0 = blockIdx.x * 64;
    const int count = counts[e];
    const int tid = threadIdx.x;
    const int wave = tid >> 6;
    const int lane = tid & 63;
    const int fr = lane & 15;
    const int fq = lane >> 4;
    const int wr = wave >> 1;   // wave M-half within a 64-row tile
    const int wc = wave & 1;    // wave N-half

    __shared__ int s_off;
    __shared__ int s_tok[MW];
    __shared__ float s_w[MW];
    __shared__ __align__(16) __bf16 As[MW * LSTR];
    __shared__ __align__(16) __bf16 Bs[128 * LSTR];

    if (tid == 0) {
        int o = 0;
        for (int i = 0; i < e; ++i) o += counts[i];
        s_off = o;
    }

    const size_t wbase = (size_t)e * HIDDEN * (2 * INTER);

    // B staging geometry: thread owns 4 adjacent n (of 128), 8 k rows
    const int ng = (tid & 31) * 4;
    const int kg = tid >> 5;
    const int bwc = ng >> 6;
    const int bj = ng & 63;
    const int memcol = (bj < 32) ? (n0 + bwc * 32 + bj)
                                 : (INTER + n0 + bwc * 32 + (bj - 32));
    const float* bCol = Wgu + wbase + (size_t)(kg * 8) * (2 * INTER) + memcol;
    // A staging geometry (per 64-row tile)
    const int ar = tid >> 2;
    const int aq = tid & 3;

    for (int m0 = 0; m0 < count; m0 += MW) {
        __syncthreads();
        if (tid < MW) {
            int slot = m0 + tid;
            int t = (slot < count) ? tok_list[e * CAP + slot] : tok_list[e * CAP];
            s_tok[tid] = t;
            s_w[tid] = (slot < count) ? rw[t * NUM_EXPERTS + e] : 0.f;
        }
        __syncthreads();
        const int nt = min(3, (count - m0 + 63) >> 6);   // active 64-row tiles

        const __bf16* aRow[3];
#pragma unroll
        for (int mt = 0; mt < 3; ++mt)
            aRow[mt] = (mt < nt) ? (xb + (size_t)s_tok[mt * 64 + ar] * HIDDEN + aq * 16)
                                 : xb;

        bf16x8 qa[3][2];
        float4 qb[8];
        auto loadA = [&](int kb) {
#pragma unroll
            for (int mt = 0; mt < 3; ++mt)
                if (mt < nt) {
                    const bf16x8* s = (const bf16x8*)(aRow[mt] + kb);
                    qa[mt][0] = s[0];
                    qa[mt][1] = s[1];
                }
        };
        auto loadB = [&](int kb) {
#pragma unroll
            for (int r8 = 0; r8 < 8; ++r8)
                qb[r8] = *(const float4*)(bCol + (size_t)(kb + r8) * (2 * INTER));
        };
        auto writeA = [&]() {
#pragma unroll
            for (int mt = 0; mt < 3; ++mt)
                if (mt < nt) {
                    *(bf16x8*)&As[swz(mt * 64 + ar, 2 * aq)] = qa[mt][0];
                    *(bf16x8*)&As[swz(mt * 64 + ar, 2 * aq + 1)] = qa[mt][1];
                }
        };
        auto writeB = [&]() {
#pragma unroll
            for (int c = 0; c < 4; ++c) {
                bf16x8 p;
#pragma unroll
                for (int r8 = 0; r8 < 8; ++r8)
                    p[r8] = (__bf16)((const float*)&qb[r8])[c];
                *(bf16x8*)&Bs[swz(ng + c, kg)] = p;
            }
        };

        floatx4 acc[3][2][4];
#pragma unroll
        for (int mt = 0; mt < 3; ++mt)
#pragma unroll
            for (int ms = 0; ms < 2; ++ms)
#pragma unroll
                for (int nf = 0; nf < 4; ++nf)
                    acc[mt][ms][nf] = (floatx4){0.f, 0.f, 0.f, 0.f};

        // prologue: stage K-tile 0
        loadA(0); loadB(0);
        writeA(); writeB();
        __syncthreads();

        for (int k0 = 0; k0 < HIDDEN; k0 += BK) {
            const bool hn = (k0 + BK < HIDDEN);
            if (hn) { loadA(k0 + BK); loadB(k0 + BK); }   // issue-early

#pragma unroll
            for (int ks = 0; ks < 2; ++ks) {
                bf16x8 bfr[4];
#pragma unroll
                for (int nf = 0; nf < 4; ++nf)
                    bfr[nf] = *(const bf16x8*)&Bs[swz(wc * 64 + nf * 16 + fr, ks * 4 + fq)];
#pragma unroll
                for (int mt = 0; mt < 3; ++mt)
                    if (mt < nt) {
                        bf16x8 af[2];
#pragma unroll
                        for (int ms = 0; ms < 2; ++ms)
                            af[ms] = *(const bf16x8*)&As[swz(mt * 64 + wr * 32 + ms * 16 + fr, ks * 4 + fq)];
#pragma unroll
                        for (int ms = 0; ms < 2; ++ms)
#pragma unroll
                            for (int nf = 0; nf < 4; ++nf)
                                acc[mt][ms][nf] = __builtin_amdgcn_mfma_f32_16x16x32_bf16(
                                    af[ms], bfr[nf], acc[mt][ms][nf], 0, 0, 0);
                    }
            }
            __syncthreads();
            if (hn) { writeA(); writeB(); }               // write-late
            __syncthreads();
        }

        // epilogue: silu(gate)*up*rw -> act bf16 (frags nf<2 gate, nf>=2 up)
        const int off = s_off;
#pragma unroll
        for (int mt = 0; mt < 3; ++mt)
            if (mt < nt) {
                int rbase = mt * 64 + wr * 32;
#pragma unroll
                for (int ms = 0; ms < 2; ++ms) {
                    int rb = rbase + ms * 16 + fq * 4;
#pragma unroll
                    for (int i = 0; i < 4; ++i) {
                        int slot = m0 + rb + i;
                        if (slot < count) {
                            float w = s_w[rb + i];
#pragma unroll
                            for (int nf = 0; nf < 2; ++nf) {
                                float gv = acc[mt][ms][nf][i];
                                float uv = acc[mt][ms][nf + 2][i];
                                float a = gv / (1.f + __expf(-gv)) * uv * w;
                                act[(size_t)(off + slot) * INTER + n0 + wc * 32 + nf * 16 + fr] = (__bf16)a;
                            }
                        }
                    }
                }
            }
    }
}

// ------------------------------------------------- gemm2: act @ Wd -> out ---
// grid (HIDDEN/128, E): one block per 128 out-cols, all tokens of the expert.
__global__ __launch_bounds__(256, 2) void gemm2_kernel(
    const __bf16* __restrict__ act, const float* __restrict__ Wd,
    const int* __restrict__ counts, const int* __restrict__ tok_list,
    float* __restrict__ out) {
    const int e = blockIdx.y;
    const int n0 = blockIdx.x * 128;
    const int count = counts[e];
    const int tid = threadIdx.x;
    const int wave = tid >> 6;
    const int lane = tid & 63;
    const int fr = lane & 15;
    const int fq = lane >> 4;
    const int wr = wave >> 1;
    const int wc = wave & 1;

    __shared__ int s_off;
    __shared__ int s_tok[MW];
    __shared__ __align__(16) __bf16 As[MW * LSTR];
    __shared__ __align__(16) __bf16 Bs[128 * LSTR];

    if (tid == 0) {
        int o = 0;
        for (int i = 0; i < e; ++i) o += counts[i];
        s_off = o;
    }

    const size_t wbase = (size_t)e * INTER * HIDDEN;
    const int ng = (tid & 31) * 4;
    const int kg = tid >> 5;
    const float* bCol = Wd + wbase + (size_t)(kg * 8) * HIDDEN + n0 + ng;
    const int ar = tid >> 2;
    const int aq = tid & 3;

    for (int m0 = 0; m0 < count; m0 += MW) {
        __syncthreads();
        if (tid < MW) {
            int slot = m0 + tid;
            s_tok[tid] = (slot < count) ? tok_list[e * CAP + slot] : 0;
        }
        __syncthreads();
        const int nt = min(3, (count - m0 + 63) >> 6);

        const __bf16* aRow[3];
#pragma unroll
        for (int mt = 0; mt < 3; ++mt)
            aRow[mt] = act + (size_t)(s_off + min(m0 + mt * 64 + ar, count - 1)) * INTER + aq * 16;

        bf16x8 qa[3][2];
        float4 qb[8];
        auto loadA = [&](int kb) {
#pragma unroll
            for (int mt = 0; mt < 3; ++mt)
                if (mt < nt) {
                    const bf16x8* s = (const bf16x8*)(aRow[mt] + kb);
                    qa[mt][0] = s[0];
                    qa[mt][1] = s[1];
                }
        };
        auto loadB = [&](int kb) {
#pragma unroll
            for (int r8 = 0; r8 < 8; ++r8)
                qb[r8] = *(const float4*)(bCol + (size_t)(kb + r8) * HIDDEN);
        };
        auto writeA = [&]() {
#pragma unroll
            for (int mt = 0; mt < 3; ++mt)
                if (mt < nt) {
                    *(bf16x8*)&As[swz(mt * 64 + ar, 2 * aq)] = qa[mt][0];
                    *(bf16x8*)&As[swz(mt * 64 + ar, 2 * aq + 1)] = qa[mt][1];
                }
        };
        auto writeB = [&]() {
#pragma unroll
            for (int c = 0; c < 4; ++c) {
                bf16x8 p;
#pragma unroll
                for (int r8 = 0; r8 < 8; ++r8)
                    p[r8] = (__bf16)((const float*)&qb[r8])[c];
                *(bf16x8*)&Bs[swz(ng + c, kg)] = p;
            }
        };

        floatx4 acc[3][2][4];
#pragma unroll
        for (int mt = 0; mt < 3; ++mt)
#pragma unroll
            for (int ms = 0; ms < 2; ++ms)
#pragma unroll
                for (int nf = 0; nf < 4; ++nf)
                    acc[mt][ms][nf] = (floatx4){0.f, 0.f, 0.f, 0.f};

        // prologue
        loadA(0); loadB(0);
        writeA(); writeB();
        __syncthreads();

        for (int k0 = 0; k0 < INTER; k0 += BK) {
            const bool hn = (k0 + BK < INTER);
            if (hn) { loadA(k0 + BK); loadB(k0 + BK); }

#pragma unroll
            for (int ks = 0; ks < 2; ++ks) {
                bf16x8 bfr[4];
#pragma unroll
                for (int nf = 0; nf < 4; ++nf)
                    bfr[nf] = *(const bf16x8*)&Bs[swz(wc * 64 + nf * 16 + fr, ks * 4 + fq)];
#pragma unroll
                for (int mt = 0; mt < 3; ++mt)
                    if (mt < nt) {
                        bf16x8 af[2];
#pragma unroll
                        for (int ms = 0; ms < 2; ++ms)
                            af[ms] = *(const bf16x8*)&As[swz(mt * 64 + wr * 32 + ms * 16 + fr, ks * 4 + fq)];
#pragma unroll
                        for (int ms = 0; ms < 2; ++ms)
#pragma unroll
                            for (int nf = 0; nf < 4; ++nf)
                                acc[mt][ms][nf] = __builtin_amdgcn_mfma_f32_16x16x32_bf16(
                                    af[ms], bfr[nf], acc[mt][ms][nf], 0, 0, 0);
                    }
            }
            __syncthreads();
            if (hn) { writeA(); writeB(); }
            __syncthreads();
        }

        // epilogue: scatter-accumulate f32 atomics
#pragma unroll
        for (int mt = 0; mt < 3; ++mt)
            if (mt < nt) {
#pragma unroll
                for (int ms = 0; ms < 2; ++ms) {
                    int rb = mt * 64 + wr * 32 + ms * 16 + fq * 4;
#pragma unroll
                    for (int i = 0; i < 4; ++i) {
                        int slot = m0 + rb + i;
                        if (slot < count) {
                            int t = s_tok[rb + i];
#pragma unroll
                            for (int nf = 0; nf < 4; ++nf)
                                atomicAdd(&out[(size_t)t * HIDDEN + n0 + wc * 64 + nf * 16 + fr],
                                          acc[mt][ms][nf][i]);
                        }
                    }
                }
            }
    }
}

// ---------------------------------------------------------------- launch ----
extern "C" void kernel_launch(void* const* d_in, const int* in_sizes, int n_in,
                              void* d_out, int out_size, void* d_ws, size_t ws_size,
                              hipStream_t stream) {
    const float* x   = (const float*)d_in[0];
    const float* rw  = (const float*)d_in[1];
    const float* Wgu = (const float*)d_in[2];
    const float* Wd  = (const float*)d_in[3];
    const int*   ri  = (const int*)d_in[4];
    float* out = (float*)d_out;

    int* counts   = (int*)d_ws;
    int* tok_list = (int*)((char*)d_ws + 512);
    __bf16* act   = (__bf16*)((char*)d_ws + 512 + NUM_EXPERTS * CAP * 4);
    __bf16* xb    = (__bf16*)((char*)d_ws + 512 + NUM_EXPERTS * CAP * 4
                              + (size_t)NUM_EXPERTS * CAP * INTER * 2);

    hipMemsetAsync(d_ws, 0, 512, stream);
    hipMemsetAsync(d_out, 0, (size_t)T_TOKENS * HIDDEN * sizeof(float), stream);

    conv_kernel<<<dim3(T_TOKENS * HIDDEN / (256 * 8)), 256, 0, stream>>>(x, xb);
    route_kernel<<<dim3(T_TOKENS / 256), 256, 0, stream>>>(ri, counts, tok_list);
    gemm1_kernel<<<dim3(INTER / 64, NUM_EXPERTS), 256, 0, stream>>>(xb, rw, Wgu, counts, tok_list, act);
    gemm2_kernel<<<dim3(HIDDEN / 128, NUM_EXPERTS), 256, 0, stream>>>(act, Wd, counts, tok_list, out);
}

// Round 5
// 703.016 us; speedup vs baseline: 1.0738x; 1.0036x over previous
//
#include <hip/hip_runtime.h>
#include <hip/hip_bf16.h>

#define NUM_EXPERTS 32
#define HIDDEN 2048
#define INTER 768
#define TOPK 4
#define T_TOKENS 1024
#define CAP 1024

#define MW 192      // token window per block (3 x 64-row MFMA tiles)
#define BK 64       // K step
#define LSTR 72     // LDS row stride in bf16 elements (16B-multiple)

typedef __bf16 bf16x8 __attribute__((ext_vector_type(8)));
typedef float floatx4 __attribute__((ext_vector_type(4)));

// XOR-swizzled LDS element offset: row-major stride LSTR, 8-elem (16B) k-blocks
// swizzled by row>>2 to break the staging-write bank pattern.
__device__ __forceinline__ int swz(int row, int kq) {
    return row * LSTR + (((kq ^ (row >> 2)) & 7) << 3);
}

// ---------------------------------------------------------------- routing ---
__global__ void route_kernel(const int* __restrict__ ri, int* __restrict__ counts,
                             int* __restrict__ tok_list) {
    int t = blockIdx.x * blockDim.x + threadIdx.x;
    if (t >= T_TOKENS) return;
    int idx[TOPK];
#pragma unroll
    for (int j = 0; j < TOPK; ++j) idx[j] = ri[t * TOPK + j];
#pragma unroll
    for (int j = 0; j < TOPK; ++j) {
        int e = idx[j];
        bool dup = false;
#pragma unroll
        for (int l = 0; l < TOPK; ++l)
            if (l < j && idx[l] == e) dup = true;
        if (!dup) {
            int s = atomicAdd(&counts[e], 1);
            tok_list[e * CAP + s] = t;
        }
    }
}

// ------------------------------------------------ x -> bf16 pre-convert ----
__global__ __launch_bounds__(256) void conv_kernel(const float* __restrict__ x,
                                                   __bf16* __restrict__ xb) {
    int i = (blockIdx.x * 256 + threadIdx.x) * 8;
    float4 f0 = *(const float4*)(x + i);
    float4 f1 = *(const float4*)(x + i + 4);
    bf16x8 p;
    p[0] = (__bf16)f0.x; p[1] = (__bf16)f0.y; p[2] = (__bf16)f0.z; p[3] = (__bf16)f0.w;
    p[4] = (__bf16)f1.x; p[5] = (__bf16)f1.y; p[6] = (__bf16)f1.z; p[7] = (__bf16)f1.w;
    *(bf16x8*)(xb + i) = p;
}

// ------------------------------------------------------- gemm1: x @ Wgu -----
// grid (INTER/32 = 24, E): N-split keeps weight-once (each block reads a
// DISTINCT 32-col gate+up slab exactly once) while giving 768 blocks = 3/CU.
// MFMA-N = 64, interleaved in 16-col groups: Bs rows [0,16)=gate[0,16),
// [16,32)=up[0,16), [32,48)=gate[16,32), [48,64)=up[16,32) so each wave owns
// gate AND up fragments of the same 16 output cols (in-wave SwiGLU).
// T14: next K-tile loads issued before compute, written after barrier.
__global__ __launch_bounds__(256, 3) void gemm1_kernel(
    const __bf16* __restrict__ xb, const float* __restrict__ rw,
    const float* __restrict__ Wgu, const int* __restrict__ counts,
    const int* __restrict__ tok_list, __bf16* __restrict__ act) {
    const int e = blockIdx.y;
    const int n0 = blockIdx.x * 32;
    const int count = counts[e];
    const int tid = threadIdx.x;
    const int wave = tid >> 6;
    const int lane = tid & 63;
    const int fr = lane & 15;
    const int fq = lane >> 4;
    const int wr = wave >> 1;   // wave M-half within a 64-row tile
    const int wc = wave & 1;    // wave 16-col group

    __shared__ int s_off;
    __shared__ int s_tok[MW];
    __shared__ float s_w[MW];
    __shared__ __align__(16) __bf16 As[MW * LSTR];
    __shared__ __align__(16) __bf16 Bs[64 * LSTR];

    if (tid == 0) {
        int o = 0;
        for (int i = 0; i < e; ++i) o += counts[i];
        s_off = o;
    }

    const size_t wbase = (size_t)e * HIDDEN * (2 * INTER);

    // B staging: thread owns 2 adjacent Bs rows (one float2/k-row), 8 k rows
    const int brow = (tid & 31) * 2;        // Bs row pair base (0..62)
    const int kg = tid >> 5;                // 8-k group (0..7)
    const int bhalf = (brow >> 4) & 1;      // 0=gate, 1=up
    const int bcolm = n0 + ((brow >> 5) << 4) + (brow & 15) + (bhalf ? INTER : 0);
    const float* bCol = Wgu + wbase + (size_t)(kg * 8) * (2 * INTER) + bcolm;
    // A staging geometry (per 64-row tile)
    const int ar = tid >> 2;
    const int aq = tid & 3;

    for (int m0 = 0; m0 < count; m0 += MW) {
        __syncthreads();
        if (tid < MW) {
            int slot = m0 + tid;
            int t = (slot < count) ? tok_list[e * CAP + slot] : tok_list[e * CAP];
            s_tok[tid] = t;
            s_w[tid] = (slot < count) ? rw[t * NUM_EXPERTS + e] : 0.f;
        }
        __syncthreads();
        const int nt = min(3, (count - m0 + 63) >> 6);   // active 64-row tiles

        const __bf16* aRow[3];
#pragma unroll
        for (int mt = 0; mt < 3; ++mt)
            aRow[mt] = (mt < nt) ? (xb + (size_t)s_tok[mt * 64 + ar] * HIDDEN + aq * 16)
                                 : xb;

        bf16x8 qa[3][2];
        float2 qb[8];
        auto loadA = [&](int kb) {
#pragma unroll
            for (int mt = 0; mt < 3; ++mt)
                if (mt < nt) {
                    const bf16x8* s = (const bf16x8*)(aRow[mt] + kb);
                    qa[mt][0] = s[0];
                    qa[mt][1] = s[1];
                }
        };
        auto loadB = [&](int kb) {
#pragma unroll
            for (int r8 = 0; r8 < 8; ++r8)
                qb[r8] = *(const float2*)(bCol + (size_t)(kb + r8) * (2 * INTER));
        };
        auto writeA = [&]() {
#pragma unroll
            for (int mt = 0; mt < 3; ++mt)
                if (mt < nt) {
                    *(bf16x8*)&As[swz(mt * 64 + ar, 2 * aq)] = qa[mt][0];
                    *(bf16x8*)&As[swz(mt * 64 + ar, 2 * aq + 1)] = qa[mt][1];
                }
        };
        auto writeB = [&]() {
#pragma unroll
            for (int c = 0; c < 2; ++c) {
                bf16x8 p;
#pragma unroll
                for (int r8 = 0; r8 < 8; ++r8)
                    p[r8] = (__bf16)((const float*)&qb[r8])[c];
                *(bf16x8*)&Bs[swz(brow + c, kg)] = p;
            }
        };

        floatx4 acc[3][2][2];
#pragma unroll
        for (int mt = 0; mt < 3; ++mt)
#pragma unroll
            for (int ms = 0; ms < 2; ++ms)
#pragma unroll
                for (int nf = 0; nf < 2; ++nf)
                    acc[mt][ms][nf] = (floatx4){0.f, 0.f, 0.f, 0.f};

        // prologue: stage K-tile 0
        loadA(0); loadB(0);
        writeA(); writeB();
        __syncthreads();

        for (int k0 = 0; k0 < HIDDEN; k0 += BK) {
            const bool hn = (k0 + BK < HIDDEN);
            if (hn) { loadA(k0 + BK); loadB(k0 + BK); }   // issue-early

#pragma unroll
            for (int ks = 0; ks < 2; ++ks) {
                bf16x8 bfr[2];
#pragma unroll
                for (int nf = 0; nf < 2; ++nf)
                    bfr[nf] = *(const bf16x8*)&Bs[swz(wc * 32 + nf * 16 + fr, ks * 4 + fq)];
#pragma unroll
                for (int mt = 0; mt < 3; ++mt)
                    if (mt < nt) {
                        bf16x8 af[2];
#pragma unroll
                        for (int ms = 0; ms < 2; ++ms)
                            af[ms] = *(const bf16x8*)&As[swz(mt * 64 + wr * 32 + ms * 16 + fr, ks * 4 + fq)];
#pragma unroll
                        for (int ms = 0; ms < 2; ++ms)
#pragma unroll
                            for (int nf = 0; nf < 2; ++nf)
                                acc[mt][ms][nf] = __builtin_amdgcn_mfma_f32_16x16x32_bf16(
                                    af[ms], bfr[nf], acc[mt][ms][nf], 0, 0, 0);
                    }
            }
            __syncthreads();
            if (hn) { writeA(); writeB(); }               // write-late
            __syncthreads();
        }

        // epilogue: nf=0 is gate, nf=1 is up for the SAME 16 cols (wc group)
        const int off = s_off;
#pragma unroll
        for (int mt = 0; mt < 3; ++mt)
            if (mt < nt) {
#pragma unroll
                for (int ms = 0; ms < 2; ++ms) {
                    int rb = mt * 64 + wr * 32 + ms * 16 + fq * 4;
#pragma unroll
                    for (int i = 0; i < 4; ++i) {
                        int slot = m0 + rb + i;
                        if (slot < count) {
                            float w = s_w[rb + i];
                            float gv = acc[mt][ms][0][i];
                            float uv = acc[mt][ms][1][i];
                            float a = gv / (1.f + __expf(-gv)) * uv * w;
                            act[(size_t)(off + slot) * INTER + n0 + wc * 16 + fr] = (__bf16)a;
                        }
                    }
                }
            }
    }
}

// ------------------------------------------------- gemm2: act @ Wd -> out ---
// grid (HIDDEN/64 = 32, E) = 1024 blocks = 4/CU; weight-once preserved.
__global__ __launch_bounds__(256, 3) void gemm2_kernel(
    const __bf16* __restrict__ act, const float* __restrict__ Wd,
    const int* __restrict__ counts, const int* __restrict__ tok_list,
    float* __restrict__ out) {
    const int e = blockIdx.y;
    const int n0 = blockIdx.x * 64;
    const int count = counts[e];
    const int tid = threadIdx.x;
    const int wave = tid >> 6;
    const int lane = tid & 63;
    const int fr = lane & 15;
    const int fq = lane >> 4;
    const int wr = wave >> 1;
    const int wc = wave & 1;

    __shared__ int s_off;
    __shared__ int s_tok[MW];
    __shared__ __align__(16) __bf16 As[MW * LSTR];
    __shared__ __align__(16) __bf16 Bs[64 * LSTR];

    if (tid == 0) {
        int o = 0;
        for (int i = 0; i < e; ++i) o += counts[i];
        s_off = o;
    }

    const size_t wbase = (size_t)e * INTER * HIDDEN;
    // B staging: 2 adjacent out-cols per thread, 8 k rows
    const int brow = (tid & 31) * 2;
    const int kg = tid >> 5;
    const float* bCol = Wd + wbase + (size_t)(kg * 8) * HIDDEN + n0 + brow;
    const int ar = tid >> 2;
    const int aq = tid & 3;

    for (int m0 = 0; m0 < count; m0 += MW) {
        __syncthreads();
        if (tid < MW) {
            int slot = m0 + tid;
            s_tok[tid] = (slot < count) ? tok_list[e * CAP + slot] : 0;
        }
        __syncthreads();
        const int nt = min(3, (count - m0 + 63) >> 6);

        const __bf16* aRow[3];
#pragma unroll
        for (int mt = 0; mt < 3; ++mt)
            aRow[mt] = act + (size_t)(s_off + min(m0 + mt * 64 + ar, count - 1)) * INTER + aq * 16;

        bf16x8 qa[3][2];
        float2 qb[8];
        auto loadA = [&](int kb) {
#pragma unroll
            for (int mt = 0; mt < 3; ++mt)
                if (mt < nt) {
                    const bf16x8* s = (const bf16x8*)(aRow[mt] + kb);
                    qa[mt][0] = s[0];
                    qa[mt][1] = s[1];
                }
        };
        auto loadB = [&](int kb) {
#pragma unroll
            for (int r8 = 0; r8 < 8; ++r8)
                qb[r8] = *(const float2*)(bCol + (size_t)(kb + r8) * HIDDEN);
        };
        auto writeA = [&]() {
#pragma unroll
            for (int mt = 0; mt < 3; ++mt)
                if (mt < nt) {
                    *(bf16x8*)&As[swz(mt * 64 + ar, 2 * aq)] = qa[mt][0];
                    *(bf16x8*)&As[swz(mt * 64 + ar, 2 * aq + 1)] = qa[mt][1];
                }
        };
        auto writeB = [&]() {
#pragma unroll
            for (int c = 0; c < 2; ++c) {
                bf16x8 p;
#pragma unroll
                for (int r8 = 0; r8 < 8; ++r8)
                    p[r8] = (__bf16)((const float*)&qb[r8])[c];
                *(bf16x8*)&Bs[swz(brow + c, kg)] = p;
            }
        };

        floatx4 acc[3][2][2];
#pragma unroll
        for (int mt = 0; mt < 3; ++mt)
#pragma unroll
            for (int ms = 0; ms < 2; ++ms)
#pragma unroll
                for (int nf = 0; nf < 2; ++nf)
                    acc[mt][ms][nf] = (floatx4){0.f, 0.f, 0.f, 0.f};

        // prologue
        loadA(0); loadB(0);
        writeA(); writeB();
        __syncthreads();

        for (int k0 = 0; k0 < INTER; k0 += BK) {
            const bool hn = (k0 + BK < INTER);
            if (hn) { loadA(k0 + BK); loadB(k0 + BK); }

#pragma unroll
            for (int ks = 0; ks < 2; ++ks) {
                bf16x8 bfr[2];
#pragma unroll
                for (int nf = 0; nf < 2; ++nf)
                    bfr[nf] = *(const bf16x8*)&Bs[swz(wc * 32 + nf * 16 + fr, ks * 4 + fq)];
#pragma unroll
                for (int mt = 0; mt < 3; ++mt)
                    if (mt < nt) {
                        bf16x8 af[2];
#pragma unroll
                        for (int ms = 0; ms < 2; ++ms)
                            af[ms] = *(const bf16x8*)&As[swz(mt * 64 + wr * 32 + ms * 16 + fr, ks * 4 + fq)];
#pragma unroll
                        for (int ms = 0; ms < 2; ++ms)
#pragma unroll
                            for (int nf = 0; nf < 2; ++nf)
                                acc[mt][ms][nf] = __builtin_amdgcn_mfma_f32_16x16x32_bf16(
                                    af[ms], bfr[nf], acc[mt][ms][nf], 0, 0, 0);
                    }
            }
            __syncthreads();
            if (hn) { writeA(); writeB(); }
            __syncthreads();
        }

        // epilogue: scatter-accumulate f32 atomics
#pragma unroll
        for (int mt = 0; mt < 3; ++mt)
            if (mt < nt) {
#pragma unroll
                for (int ms = 0; ms < 2; ++ms) {
                    int rb = mt * 64 + wr * 32 + ms * 16 + fq * 4;
#pragma unroll
                    for (int i = 0; i < 4; ++i) {
                        int slot = m0 + rb + i;
                        if (slot < count) {
                            int t = s_tok[rb + i];
#pragma unroll
                            for (int nf = 0; nf < 2; ++nf)
                                atomicAdd(&out[(size_t)t * HIDDEN + n0 + wc * 32 + nf * 16 + fr],
                                          acc[mt][ms][nf][i]);
                        }
                    }
                }
            }
    }
}

// ---------------------------------------------------------------- launch ----
extern "C" void kernel_launch(void* const* d_in, const int* in_sizes, int n_in,
                              void* d_out, int out_size, void* d_ws, size_t ws_size,
                              hipStream_t stream) {
    const float* x   = (const float*)d_in[0];
    const float* rw  = (const float*)d_in[1];
    const float* Wgu = (const float*)d_in[2];
    const float* Wd  = (const float*)d_in[3];
    const int*   ri  = (const int*)d_in[4];
    float* out = (float*)d_out;

    int* counts   = (int*)d_ws;
    int* tok_list = (int*)((char*)d_ws + 512);
    __bf16* act   = (__bf16*)((char*)d_ws + 512 + NUM_EXPERTS * CAP * 4);
    __bf16* xb    = (__bf16*)((char*)d_ws + 512 + NUM_EXPERTS * CAP * 4
                              + (size_t)NUM_EXPERTS * CAP * INTER * 2);

    hipMemsetAsync(d_ws, 0, 512, stream);
    hipMemsetAsync(d_out, 0, (size_t)T_TOKENS * HIDDEN * sizeof(float), stream);

    conv_kernel<<<dim3(T_TOKENS * HIDDEN / (256 * 8)), 256, 0, stream>>>(x, xb);
    route_kernel<<<dim3(T_TOKENS / 256), 256, 0, stream>>>(ri, counts, tok_list);
    gemm1_kernel<<<dim3(INTER / 32, NUM_EXPERTS), 256, 0, stream>>>(xb, rw, Wgu, counts, tok_list, act);
    gemm2_kernel<<<dim3(HIDDEN / 64, NUM_EXPERTS), 256, 0, stream>>>(act, Wd, counts, tok_list, out);
}

// Round 6
// 698.848 us; speedup vs baseline: 1.0803x; 1.0060x over previous
//
#include <hip/hip_runtime.h>
#include <hip/hip_bf16.h>

#define NUM_EXPERTS 32
#define HIDDEN 2048
#define INTER 768
#define TOPK 4
#define T_TOKENS 1024
#define CAP 1024

#define MW 192      // token window per block (3 x 64-row MFMA tiles)
#define BK 64       // K step
#define LSTR 72     // LDS row stride in bf16 elements (16B-multiple)

typedef __bf16 bf16x8 __attribute__((ext_vector_type(8)));
typedef float floatx4 __attribute__((ext_vector_type(4)));

// XOR-swizzled LDS element offset: row-major stride LSTR, 8-elem (16B) k-blocks.
// row&7 (full 8-period) -> both staging writes and fragment reads are 2-way
// (free) instead of the old row>>2's 4-way.
__device__ __forceinline__ int swz(int row, int kq) {
    return row * LSTR + (((kq ^ (row & 7)) & 7) << 3);
}

// ------------------------------------------------ x -> bf16 + zero counts ---
__global__ __launch_bounds__(256) void conv_kernel(const float* __restrict__ x,
                                                   __bf16* __restrict__ xb,
                                                   int* __restrict__ counts) {
    if (blockIdx.x == 0 && threadIdx.x < NUM_EXPERTS) counts[threadIdx.x] = 0;
    int i = (blockIdx.x * 256 + threadIdx.x) * 8;
    float4 f0 = *(const float4*)(x + i);
    float4 f1 = *(const float4*)(x + i + 4);
    bf16x8 p;
    p[0] = (__bf16)f0.x; p[1] = (__bf16)f0.y; p[2] = (__bf16)f0.z; p[3] = (__bf16)f0.w;
    p[4] = (__bf16)f1.x; p[5] = (__bf16)f1.y; p[6] = (__bf16)f1.z; p[7] = (__bf16)f1.w;
    *(bf16x8*)(xb + i) = p;
}

// ---------------------------------------------------------------- routing ---
// Also emits the inverse map inv[t][j] = (e<<16)|slot (or -1 for dups) so the
// combine kernel can gather partials without atomics in gemm2.
__global__ void route_kernel(const int* __restrict__ ri, int* __restrict__ counts,
                             int* __restrict__ tok_list, int* __restrict__ inv) {
    int t = blockIdx.x * blockDim.x + threadIdx.x;
    if (t >= T_TOKENS) return;
    int idx[TOPK];
#pragma unroll
    for (int j = 0; j < TOPK; ++j) idx[j] = ri[t * TOPK + j];
#pragma unroll
    for (int j = 0; j < TOPK; ++j) {
        int e = idx[j];
        bool dup = false;
#pragma unroll
        for (int l = 0; l < TOPK; ++l)
            if (l < j && idx[l] == e) dup = true;
        if (!dup) {
            int s = atomicAdd(&counts[e], 1);
            tok_list[e * CAP + s] = t;
            inv[t * TOPK + j] = (e << 16) | s;
        } else {
            inv[t * TOPK + j] = -1;
        }
    }
}

// ------------------------------------------------------- gemm1: x @ Wgu -----
// grid (INTER/32 = 24, E): weight-once N-split, 768 blocks (3-4/CU).
// MFMA-N = 64 with gate/up interleaved in 16-col groups for in-wave SwiGLU.
// T14: next K-tile loads issued before compute, written after barrier.
__global__ __launch_bounds__(256, 3) void gemm1_kernel(
    const __bf16* __restrict__ xb, const float* __restrict__ rw,
    const float* __restrict__ Wgu, const int* __restrict__ counts,
    const int* __restrict__ tok_list, __bf16* __restrict__ act) {
    const int e = blockIdx.y;
    const int n0 = blockIdx.x * 32;
    const int count = counts[e];
    const int tid = threadIdx.x;
    const int wave = tid >> 6;
    const int lane = tid & 63;
    const int fr = lane & 15;
    const int fq = lane >> 4;
    const int wr = wave >> 1;   // wave M-half within a 64-row tile
    const int wc = wave & 1;    // wave 16-col group

    __shared__ int s_off;
    __shared__ int s_tok[MW];
    __shared__ float s_w[MW];
    __shared__ __align__(16) __bf16 As[MW * LSTR];
    __shared__ __align__(16) __bf16 Bs[64 * LSTR];

    if (tid == 0) {
        int o = 0;
        for (int i = 0; i < e; ++i) o += counts[i];
        s_off = o;
    }

    const size_t wbase = (size_t)e * HIDDEN * (2 * INTER);

    // B staging: thread owns 2 adjacent Bs rows (one float2/k-row), 8 k rows
    const int brow = (tid & 31) * 2;        // Bs row pair base (0..62)
    const int kg = tid >> 5;                // 8-k group (0..7)
    const int bhalf = (brow >> 4) & 1;      // 0=gate, 1=up
    const int bcolm = n0 + ((brow >> 5) << 4) + (brow & 15) + (bhalf ? INTER : 0);
    const float* bCol = Wgu + wbase + (size_t)(kg * 8) * (2 * INTER) + bcolm;
    // A staging geometry (per 64-row tile)
    const int ar = tid >> 2;
    const int aq = tid & 3;

    for (int m0 = 0; m0 < count; m0 += MW) {
        __syncthreads();
        if (tid < MW) {
            int slot = m0 + tid;
            int t = (slot < count) ? tok_list[e * CAP + slot] : tok_list[e * CAP];
            s_tok[tid] = t;
            s_w[tid] = (slot < count) ? rw[t * NUM_EXPERTS + e] : 0.f;
        }
        __syncthreads();
        const int nt = min(3, (count - m0 + 63) >> 6);   // active 64-row tiles

        const __bf16* aRow[3];
#pragma unroll
        for (int mt = 0; mt < 3; ++mt)
            aRow[mt] = (mt < nt) ? (xb + (size_t)s_tok[mt * 64 + ar] * HIDDEN + aq * 16)
                                 : xb;

        bf16x8 qa[3][2];
        float2 qb[8];
        auto loadA = [&](int kb) {
#pragma unroll
            for (int mt = 0; mt < 3; ++mt)
                if (mt < nt) {
                    const bf16x8* s = (const bf16x8*)(aRow[mt] + kb);
                    qa[mt][0] = s[0];
                    qa[mt][1] = s[1];
                }
        };
        auto loadB = [&](int kb) {
#pragma unroll
            for (int r8 = 0; r8 < 8; ++r8)
                qb[r8] = *(const float2*)(bCol + (size_t)(kb + r8) * (2 * INTER));
        };
        auto writeA = [&]() {
#pragma unroll
            for (int mt = 0; mt < 3; ++mt)
                if (mt < nt) {
                    *(bf16x8*)&As[swz(mt * 64 + ar, 2 * aq)] = qa[mt][0];
                    *(bf16x8*)&As[swz(mt * 64 + ar, 2 * aq + 1)] = qa[mt][1];
                }
        };
        auto writeB = [&]() {
#pragma unroll
            for (int c = 0; c < 2; ++c) {
                bf16x8 p;
#pragma unroll
                for (int r8 = 0; r8 < 8; ++r8)
                    p[r8] = (__bf16)((const float*)&qb[r8])[c];
                *(bf16x8*)&Bs[swz(brow + c, kg)] = p;
            }
        };

        floatx4 acc[3][2][2];
#pragma unroll
        for (int mt = 0; mt < 3; ++mt)
#pragma unroll
            for (int ms = 0; ms < 2; ++ms)
#pragma unroll
                for (int nf = 0; nf < 2; ++nf)
                    acc[mt][ms][nf] = (floatx4){0.f, 0.f, 0.f, 0.f};

        // prologue: stage K-tile 0
        loadA(0); loadB(0);
        writeA(); writeB();
        __syncthreads();

        for (int k0 = 0; k0 < HIDDEN; k0 += BK) {
            const bool hn = (k0 + BK < HIDDEN);
            if (hn) { loadA(k0 + BK); loadB(k0 + BK); }   // issue-early

#pragma unroll
            for (int ks = 0; ks < 2; ++ks) {
                bf16x8 bfr[2];
#pragma unroll
                for (int nf = 0; nf < 2; ++nf)
                    bfr[nf] = *(const bf16x8*)&Bs[swz(wc * 32 + nf * 16 + fr, ks * 4 + fq)];
#pragma unroll
                for (int mt = 0; mt < 3; ++mt)
                    if (mt < nt) {
                        bf16x8 af[2];
#pragma unroll
                        for (int ms = 0; ms < 2; ++ms)
                            af[ms] = *(const bf16x8*)&As[swz(mt * 64 + wr * 32 + ms * 16 + fr, ks * 4 + fq)];
#pragma unroll
                        for (int ms = 0; ms < 2; ++ms)
#pragma unroll
                            for (int nf = 0; nf < 2; ++nf)
                                acc[mt][ms][nf] = __builtin_amdgcn_mfma_f32_16x16x32_bf16(
                                    af[ms], bfr[nf], acc[mt][ms][nf], 0, 0, 0);
                    }
            }
            __syncthreads();
            if (hn) { writeA(); writeB(); }               // write-late
            __syncthreads();
        }

        // epilogue: nf=0 is gate, nf=1 is up for the SAME 16 cols (wc group)
        const int off = s_off;
#pragma unroll
        for (int mt = 0; mt < 3; ++mt)
            if (mt < nt) {
#pragma unroll
                for (int ms = 0; ms < 2; ++ms) {
                    int rb = mt * 64 + wr * 32 + ms * 16 + fq * 4;
#pragma unroll
                    for (int i = 0; i < 4; ++i) {
                        int slot = m0 + rb + i;
                        if (slot < count) {
                            float w = s_w[rb + i];
                            float gv = acc[mt][ms][0][i];
                            float uv = acc[mt][ms][1][i];
                            float a = gv / (1.f + __expf(-gv)) * uv * w;
                            act[(size_t)(off + slot) * INTER + n0 + wc * 16 + fr] = (__bf16)a;
                        }
                    }
                }
            }
    }
}

// ------------------------------------------------- gemm2: act @ Wd ----------
// grid (HIDDEN/64 = 32, E) = 1024 blocks; weight-once. Writes PLAIN coalesced
// stores into partial[slot_row][HIDDEN] (no atomics, no out-memset needed).
__global__ __launch_bounds__(256, 3) void gemm2_kernel(
    const __bf16* __restrict__ act, const float* __restrict__ Wd,
    const int* __restrict__ counts, const int* __restrict__ tok_list,
    float* __restrict__ partial) {
    const int e = blockIdx.y;
    const int n0 = blockIdx.x * 64;
    const int count = counts[e];
    const int tid = threadIdx.x;
    const int wave = tid >> 6;
    const int lane = tid & 63;
    const int fr = lane & 15;
    const int fq = lane >> 4;
    const int wr = wave >> 1;
    const int wc = wave & 1;

    __shared__ int s_off;
    __shared__ __align__(16) __bf16 As[MW * LSTR];
    __shared__ __align__(16) __bf16 Bs[64 * LSTR];

    if (tid == 0) {
        int o = 0;
        for (int i = 0; i < e; ++i) o += counts[i];
        s_off = o;
    }
    __syncthreads();
    const int off = s_off;

    const size_t wbase = (size_t)e * INTER * HIDDEN;
    // B staging: 2 adjacent out-cols per thread, 8 k rows
    const int brow = (tid & 31) * 2;
    const int kg = tid >> 5;
    const float* bCol = Wd + wbase + (size_t)(kg * 8) * HIDDEN + n0 + brow;
    const int ar = tid >> 2;
    const int aq = tid & 3;

    for (int m0 = 0; m0 < count; m0 += MW) {
        __syncthreads();
        const int nt = min(3, (count - m0 + 63) >> 6);

        const __bf16* aRow[3];
#pragma unroll
        for (int mt = 0; mt < 3; ++mt)
            aRow[mt] = act + (size_t)(off + min(m0 + mt * 64 + ar, count - 1)) * INTER + aq * 16;

        bf16x8 qa[3][2];
        float2 qb[8];
        auto loadA = [&](int kb) {
#pragma unroll
            for (int mt = 0; mt < 3; ++mt)
                if (mt < nt) {
                    const bf16x8* s = (const bf16x8*)(aRow[mt] + kb);
                    qa[mt][0] = s[0];
                    qa[mt][1] = s[1];
                }
        };
        auto loadB = [&](int kb) {
#pragma unroll
            for (int r8 = 0; r8 < 8; ++r8)
                qb[r8] = *(const float2*)(bCol + (size_t)(kb + r8) * HIDDEN);
        };
        auto writeA = [&]() {
#pragma unroll
            for (int mt = 0; mt < 3; ++mt)
                if (mt < nt) {
                    *(bf16x8*)&As[swz(mt * 64 + ar, 2 * aq)] = qa[mt][0];
                    *(bf16x8*)&As[swz(mt * 64 + ar, 2 * aq + 1)] = qa[mt][1];
                }
        };
        auto writeB = [&]() {
#pragma unroll
            for (int c = 0; c < 2; ++c) {
                bf16x8 p;
#pragma unroll
                for (int r8 = 0; r8 < 8; ++r8)
                    p[r8] = (__bf16)((const float*)&qb[r8])[c];
                *(bf16x8*)&Bs[swz(brow + c, kg)] = p;
            }
        };

        floatx4 acc[3][2][2];
#pragma unroll
        for (int mt = 0; mt < 3; ++mt)
#pragma unroll
            for (int ms = 0; ms < 2; ++ms)
#pragma unroll
                for (int nf = 0; nf < 2; ++nf)
                    acc[mt][ms][nf] = (floatx4){0.f, 0.f, 0.f, 0.f};

        // prologue
        loadA(0); loadB(0);
        writeA(); writeB();
        __syncthreads();

        for (int k0 = 0; k0 < INTER; k0 += BK) {
            const bool hn = (k0 + BK < INTER);
            if (hn) { loadA(k0 + BK); loadB(k0 + BK); }

#pragma unroll
            for (int ks = 0; ks < 2; ++ks) {
                bf16x8 bfr[2];
#pragma unroll
                for (int nf = 0; nf < 2; ++nf)
                    bfr[nf] = *(const bf16x8*)&Bs[swz(wc * 32 + nf * 16 + fr, ks * 4 + fq)];
#pragma unroll
                for (int mt = 0; mt < 3; ++mt)
                    if (mt < nt) {
                        bf16x8 af[2];
#pragma unroll
                        for (int ms = 0; ms < 2; ++ms)
                            af[ms] = *(const bf16x8*)&As[swz(mt * 64 + wr * 32 + ms * 16 + fr, ks * 4 + fq)];
#pragma unroll
                        for (int ms = 0; ms < 2; ++ms)
#pragma unroll
                            for (int nf = 0; nf < 2; ++nf)
                                acc[mt][ms][nf] = __builtin_amdgcn_mfma_f32_16x16x32_bf16(
                                    af[ms], bfr[nf], acc[mt][ms][nf], 0, 0, 0);
                    }
            }
            __syncthreads();
            if (hn) { writeA(); writeB(); }
            __syncthreads();
        }

        // epilogue: plain stores to slot-row partials
#pragma unroll
        for (int mt = 0; mt < 3; ++mt)
            if (mt < nt) {
#pragma unroll
                for (int ms = 0; ms < 2; ++ms) {
                    int rb = mt * 64 + wr * 32 + ms * 16 + fq * 4;
#pragma unroll
                    for (int i = 0; i < 4; ++i) {
                        int slot = m0 + rb + i;
                        if (slot < count) {
#pragma unroll
                            for (int nf = 0; nf < 2; ++nf)
                                partial[(size_t)(off + slot) * HIDDEN + n0 + wc * 32 + nf * 16 + fr] =
                                    acc[mt][ms][nf][i];
                        }
                    }
                }
            }
    }
}

// ----------------------------------------------- combine: sum <=4 partials --
__global__ __launch_bounds__(256) void combine_kernel(
    const float* __restrict__ partial, const int* __restrict__ counts,
    const int* __restrict__ inv, float* __restrict__ out) {
    const int t = blockIdx.x;
    __shared__ int s_off[NUM_EXPERTS];
    __shared__ int s_inv[TOPK];
    if (threadIdx.x == 0) {
        int o = 0;
        for (int i = 0; i < NUM_EXPERTS; ++i) { s_off[i] = o; o += counts[i]; }
    }
    if (threadIdx.x < TOPK) s_inv[threadIdx.x] = inv[t * TOPK + threadIdx.x];
    __syncthreads();
    const int c0 = threadIdx.x * 8;
    float4 a0 = {0.f, 0.f, 0.f, 0.f}, a1 = {0.f, 0.f, 0.f, 0.f};
#pragma unroll
    for (int j = 0; j < TOPK; ++j) {
        int v = s_inv[j];
        if (v >= 0) {
            int e = v >> 16, s = v & 0xFFFF;
            const float* p = partial + (size_t)(s_off[e] + s) * HIDDEN + c0;
            float4 b0 = ((const float4*)p)[0];
            float4 b1 = ((const float4*)p)[1];
            a0.x += b0.x; a0.y += b0.y; a0.z += b0.z; a0.w += b0.w;
            a1.x += b1.x; a1.y += b1.y; a1.z += b1.z; a1.w += b1.w;
        }
    }
    float* o = out + (size_t)t * HIDDEN + c0;
    ((float4*)o)[0] = a0;
    ((float4*)o)[1] = a1;
}

// ---------------------------------------------------------------- launch ----
extern "C" void kernel_launch(void* const* d_in, const int* in_sizes, int n_in,
                              void* d_out, int out_size, void* d_ws, size_t ws_size,
                              hipStream_t stream) {
    const float* x   = (const float*)d_in[0];
    const float* rw  = (const float*)d_in[1];
    const float* Wgu = (const float*)d_in[2];
    const float* Wd  = (const float*)d_in[3];
    const int*   ri  = (const int*)d_in[4];
    float* out = (float*)d_out;

    char* ws = (char*)d_ws;
    int* counts    = (int*)ws;                                   // 512 B
    int* tok_list  = (int*)(ws + 512);                           // 128 KiB
    __bf16* act    = (__bf16*)(ws + 512 + NUM_EXPERTS * CAP * 4);            // 48 MiB
    __bf16* xb     = (__bf16*)((char*)act + (size_t)NUM_EXPERTS * CAP * INTER * 2); // 4 MiB
    int* inv       = (int*)((char*)xb + (size_t)T_TOKENS * HIDDEN * 2);      // 16 KiB
    float* partial = (float*)((char*)inv + (size_t)T_TOKENS * TOPK * 4);     // 33.5 MiB

    conv_kernel<<<dim3(T_TOKENS * HIDDEN / (256 * 8)), 256, 0, stream>>>(x, xb, counts);
    route_kernel<<<dim3(T_TOKENS / 256), 256, 0, stream>>>(ri, counts, tok_list, inv);
    gemm1_kernel<<<dim3(INTER / 32, NUM_EXPERTS), 256, 0, stream>>>(xb, rw, Wgu, counts, tok_list, act);
    gemm2_kernel<<<dim3(HIDDEN / 64, NUM_EXPERTS), 256, 0, stream>>>(act, Wd, counts, tok_list, partial);
    combine_kernel<<<dim3(T_TOKENS), 256, 0, stream>>>(partial, counts, inv, out);
}